// Round 5
// baseline (558.538 us; speedup 1.0000x reference)
//
#include <hip/hip_runtime.h>

// SimpleConcatAttention on MI355X — round 5: kill the per-K-step B transpose.
// Round-4 post-mortem: phase 2 (split GEMM) = 139 µs at 741 TF effective (near
// the 2-barrier structure ceiling). Phase 4 took ~140 µs for 1/3 the FLOPs —
// its per-K-step scattered-u32 B repack (key consumed transposed) dominated.
// Round 5: transpose key_hi ONCE (into the key_lo slot, dead after phase 2 —
// WS_NEED unchanged) and W's planes once; all GEMMs are now copy-staged with
// both operands k-contiguous. The scatter path is deleted from the hot GEMM.
//   0) split key -> key_hi/key_lo; split query, W (scratch in att_b region)
//   0b) transpose W_hi/W_lo -> W_hiT/W_loT
//   1) qW hi/lo = (q@W)/32            gemm_qw, all copy-staged
//   2) S = qW@key^T                   gemm_bf16<SPLIT=1> (hh+hl+lh)
//   2b) transpose key_hi -> key_hT    (into key_lo slot; key_lo dead)
//   3) masked softmax f32, dual-write f32 + bf16
//   4) out = att@key                  gemm_bf16<SPLIT=0> with key_hT
// Fallback (ws too small): round-1 fused-conversion path.

typedef float f32x4 __attribute__((ext_vector_type(4)));
typedef short bf16x8 __attribute__((ext_vector_type(8)));
typedef short s16x4 __attribute__((ext_vector_type(4)));
typedef unsigned short u16;
typedef unsigned short u16x8 __attribute__((ext_vector_type(8)));

// f32 -> bf16 (RNE) bit-twiddle (compiler-visible; proven), exact expand.
__device__ __forceinline__ u16 f2bf(float f) {
    unsigned int u = __float_as_uint(f);
    return (u16)((u + 0x7fffu + ((u >> 16) & 1u)) >> 16);
}
__device__ __forceinline__ float bf2f(u16 h) {
    return __uint_as_float(((unsigned int)h) << 16);
}

// Load 8 bf16 (two 8B halves) from LDS at two precomputed u16 offsets.
__device__ __forceinline__ bf16x8 ld2(const u16* p, int off1, int off2) {
    s16x4 a = *(const s16x4*)(p + off1);
    s16x4 b = *(const s16x4*)(p + off2);
    bf16x8 r = {a[0], a[1], a[2], a[3], b[0], b[1], b[2], b[3]};
    return r;
}

// ===========================================================================
// Round-1 fused-conversion GEMM — fallback path only (ws too small).
// ===========================================================================
#define CSTR 36
__device__ __forceinline__ int swzc(int row, int k) {
    return row * CSTR + (k ^ (((row >> 2) & 7) << 2));
}
__device__ __forceinline__ bf16x8 ld_fragc(const u16* plane, int row, int kg) {
    return ld2(plane, swzc(row, kg), swzc(row, kg + 16));
}

template<bool BT, bool SPLIT>
__global__ __launch_bounds__(256, 2) void gemm_f32conv(
    const float* __restrict__ A, const float* __restrict__ B,
    float* __restrict__ C,
    int Kd, int lda, int ldb, int ldc,
    long sA, long sB, long sC, float scale)
{
    constexpr int PLANES = SPLIT ? 2 : 1;
    __shared__ u16 As[PLANES][128 * CSTR];
    __shared__ u16 Bs[PLANES][128 * CSTR];

    const int tid  = threadIdx.x;
    const int lane = tid & 63;
    const int wave = tid >> 6;
    const int wm = (wave >> 1) * 64, wn = (wave & 1) * 64;
    const int lr = lane & 15, kg = (lane >> 4) * 4;

    const int m0 = blockIdx.y * 128, n0 = blockIdx.x * 128;
    const float* Ag = A + (long)blockIdx.z * sA + (long)m0 * lda;
    const float* Bg = B + (long)blockIdx.z * sB + (BT ? (long)n0 * ldb : (long)n0);

    f32x4 acc[4][4] = {};

    for (int k0 = 0; k0 < Kd; k0 += 32) {
        __syncthreads();
#pragma unroll
        for (int it = 0; it < 4; it++) {
            const int idx = tid + it * 256;
            const int row = idx >> 3, kc = (idx & 7) * 4;
            f32x4 v = *(const f32x4*)(Ag + (long)row * lda + k0 + kc);
            ushort4 h;
            h.x = f2bf(v[0]); h.y = f2bf(v[1]); h.z = f2bf(v[2]); h.w = f2bf(v[3]);
            *(ushort4*)&As[0][swzc(row, kc)] = h;
            if constexpr (SPLIT) {
                ushort4 l;
                l.x = f2bf(v[0] - bf2f(h.x)); l.y = f2bf(v[1] - bf2f(h.y));
                l.z = f2bf(v[2] - bf2f(h.z)); l.w = f2bf(v[3] - bf2f(h.w));
                *(ushort4*)&As[1][swzc(row, kc)] = l;
            }
        }
        if constexpr (BT) {
#pragma unroll
            for (int it = 0; it < 4; it++) {
                const int idx = tid + it * 256;
                const int row = idx >> 3, kc = (idx & 7) * 4;
                f32x4 v = *(const f32x4*)(Bg + (long)row * ldb + k0 + kc);
                ushort4 h;
                h.x = f2bf(v[0]); h.y = f2bf(v[1]); h.z = f2bf(v[2]); h.w = f2bf(v[3]);
                *(ushort4*)&Bs[0][swzc(row, kc)] = h;
                if constexpr (SPLIT) {
                    ushort4 l;
                    l.x = f2bf(v[0] - bf2f(h.x)); l.y = f2bf(v[1] - bf2f(h.y));
                    l.z = f2bf(v[2] - bf2f(h.z)); l.w = f2bf(v[3] - bf2f(h.w));
                    *(ushort4*)&Bs[1][swzc(row, kc)] = l;
                }
            }
        } else {
#pragma unroll
            for (int it = 0; it < 2; it++) {
                const int idx = tid + it * 256;
                const int kk = (idx >> 5) * 2;
                const int nc = (idx & 31) * 4;
                f32x4 v0 = *(const f32x4*)(Bg + (long)(k0 + kk) * ldb + nc);
                f32x4 v1 = *(const f32x4*)(Bg + (long)(k0 + kk + 1) * ldb + nc);
#pragma unroll
                for (int e = 0; e < 4; e++) {
                    const u16 h0 = f2bf(v0[e]), h1 = f2bf(v1[e]);
                    *(unsigned*)&Bs[0][swzc(nc + e, kk)] =
                        (unsigned)h0 | ((unsigned)h1 << 16);
                    if constexpr (SPLIT) {
                        const u16 l0 = f2bf(v0[e] - bf2f(h0));
                        const u16 l1 = f2bf(v1[e] - bf2f(h1));
                        *(unsigned*)&Bs[1][swzc(nc + e, kk)] =
                            (unsigned)l0 | ((unsigned)l1 << 16);
                    }
                }
            }
        }
        __syncthreads();

        bf16x8 ah[4], bh[4], al[4], bl[4];
#pragma unroll
        for (int i = 0; i < 4; i++) {
            ah[i] = ld_fragc(&As[0][0], wm + i * 16 + lr, kg);
            if constexpr (SPLIT) al[i] = ld_fragc(&As[1][0], wm + i * 16 + lr, kg);
        }
#pragma unroll
        for (int j = 0; j < 4; j++) {
            bh[j] = ld_fragc(&Bs[0][0], wn + j * 16 + lr, kg);
            if constexpr (SPLIT) bl[j] = ld_fragc(&Bs[1][0], wn + j * 16 + lr, kg);
        }
#pragma unroll
        for (int i = 0; i < 4; i++)
#pragma unroll
            for (int j = 0; j < 4; j++) {
                acc[i][j] = __builtin_amdgcn_mfma_f32_16x16x32_bf16(
                    ah[i], bh[j], acc[i][j], 0, 0, 0);
                if constexpr (SPLIT) {
                    acc[i][j] = __builtin_amdgcn_mfma_f32_16x16x32_bf16(
                        ah[i], bl[j], acc[i][j], 0, 0, 0);
                    acc[i][j] = __builtin_amdgcn_mfma_f32_16x16x32_bf16(
                        al[i], bh[j], acc[i][j], 0, 0, 0);
                }
            }
    }

    float* Cg = C + (long)blockIdx.z * sC + (long)(m0 + wm) * ldc + n0 + wn;
    const int rbase = (lane >> 4) * 4;
#pragma unroll
    for (int i = 0; i < 4; i++)
#pragma unroll
        for (int r = 0; r < 4; r++) {
            float* cp = Cg + (long)(i * 16 + rbase + r) * ldc + lr;
#pragma unroll
            for (int j = 0; j < 4; j++)
                cp[j * 16] = acc[i][j][r] * scale;
        }
}

// ===========================================================================
// Elementwise split: src f32 -> hi/lo bf16 planes. n4 = element count / 4.
// ===========================================================================
__global__ __launch_bounds__(256) void split_f32(
    const float* __restrict__ src, u16* __restrict__ hi, u16* __restrict__ lo,
    long n4)
{
    const long stride = (long)gridDim.x * 256;
    for (long i = (long)blockIdx.x * 256 + threadIdx.x; i < n4; i += stride) {
        f32x4 v = *(const f32x4*)(src + i * 4);
        ushort4 h, l;
        h.x = f2bf(v[0]); h.y = f2bf(v[1]); h.z = f2bf(v[2]); h.w = f2bf(v[3]);
        l.x = f2bf(v[0] - bf2f(h.x)); l.y = f2bf(v[1] - bf2f(h.y));
        l.z = f2bf(v[2] - bf2f(h.z)); l.w = f2bf(v[3] - bf2f(h.w));
        *(ushort4*)(hi + i * 4) = h;
        *(ushort4*)(lo + i * 4) = l;
    }
}

// ===========================================================================
// Tiled bf16 transpose: in [Z][R][C] -> out [Z][C][R]. R,C multiples of 64.
// 64x64 tile per block; scatter-transpose into LDS (u16 writes), aligned
// b128 coalesced writes out. Memory-bound; one-time cost replacing phase-4's
// per-K-step scatter repack.
// ===========================================================================
__global__ __launch_bounds__(256) void transpose_bf16(
    const u16* __restrict__ in, u16* __restrict__ out, int R, int C)
{
    __shared__ u16 T[64 * 72];                  // stride 72 u16 = 144 B (16B-align)
    const int tid = threadIdx.x;
    const int c0 = blockIdx.x * 64, r0 = blockIdx.y * 64;
    const long zoff = (long)blockIdx.z * R * C;
    const u16* src = in + zoff + (long)r0 * C + c0;
#pragma unroll
    for (int it = 0; it < 2; it++) {
        const int r = it * 32 + (tid >> 3), c = (tid & 7) * 8;
        u16x8 v = *(const u16x8*)(src + (long)r * C + c);
#pragma unroll
        for (int j = 0; j < 8; j++) T[(c + j) * 72 + r] = v[j];
    }
    __syncthreads();
    u16* dst = out + zoff + (long)c0 * R + r0;
#pragma unroll
    for (int it = 0; it < 2; it++) {
        const int c = it * 32 + (tid >> 3), r = (tid & 7) * 8;
        *(u16x8*)(dst + (long)c * R + r) = *(const u16x8*)&T[c * 72 + r];
    }
}

// ===========================================================================
// bf16-input MFMA GEMM, BOTH operands k-contiguous (copy staging only):
//   C[z] = scale * A[z] @ B[z]^T-style dot over k.
// A: [M][lda] bf16, B: [N][ldb] bf16. Tile 128x128, BK=32, 4 waves (64x64 each).
// SPLIT: hi/lo planes + 3-MFMA emulation; else hi-only, 1 MFMA.
// ===========================================================================
#define ASTR 40
template<bool SPLIT>
__global__ __launch_bounds__(256, 3) void gemm_bf16(
    const u16* __restrict__ Ah, const u16* __restrict__ Al,
    const u16* __restrict__ Bh, const u16* __restrict__ Bl,
    float* __restrict__ C,
    int Kd, int lda, int ldb, int ldc,
    long sA, long sB, long sC, float scale)
{
    constexpr int PL = SPLIT ? 2 : 1;
    __shared__ u16 As[PL][128 * ASTR];
    __shared__ u16 Bs[PL][128 * ASTR];

    const int tid  = threadIdx.x;
    const int lane = tid & 63;
    const int wave = tid >> 6;
    const int wm = (wave >> 1) * 64, wn = (wave & 1) * 64;
    const int lr = lane & 15, kg = (lane >> 4) * 4;

    const int m0 = blockIdx.y * 128, n0 = blockIdx.x * 128;
    const u16* Ag[PL];
    const u16* Bg[PL];
    Ag[0] = Ah + (long)blockIdx.z * sA + (long)m0 * lda;
    Bg[0] = Bh + (long)blockIdx.z * sB + (long)n0 * ldb;
    if constexpr (SPLIT) {
        Ag[1] = Al + (long)blockIdx.z * sA + (long)m0 * lda;
        Bg[1] = Bl + (long)blockIdx.z * sB + (long)n0 * ldb;
    }

    f32x4 acc[4][4] = {};

    for (int k0 = 0; k0 < Kd; k0 += 32) {
        __syncthreads();
        // ---- copy-stage A and B planes: 2 x 16B per thread per plane ----
#pragma unroll
        for (int p = 0; p < PL; p++)
#pragma unroll
            for (int it = 0; it < 2; it++) {
                const int idx = tid + it * 256;
                const int row = idx >> 2, kc = (idx & 3) * 8;
                *(u16x8*)&As[p][row * ASTR + kc] =
                    *(const u16x8*)(Ag[p] + (long)row * lda + k0 + kc);
                *(u16x8*)&Bs[p][row * ASTR + kc] =
                    *(const u16x8*)(Bg[p] + (long)row * ldb + k0 + kc);
            }
        __syncthreads();

        // ---- fragment loads ----
        bf16x8 af[PL][4], bf[PL][4];
#pragma unroll
        for (int i = 0; i < 4; i++) {
            const int r = wm + i * 16 + lr;
#pragma unroll
            for (int p = 0; p < PL; p++)
                af[p][i] = ld2(&As[p][0], r * ASTR + kg, r * ASTR + kg + 16);
        }
#pragma unroll
        for (int j = 0; j < 4; j++) {
            const int r = wn + j * 16 + lr;
#pragma unroll
            for (int p = 0; p < PL; p++)
                bf[p][j] = ld2(&Bs[p][0], r * ASTR + kg, r * ASTR + kg + 16);
        }

        // ---- MFMA ----
#pragma unroll
        for (int i = 0; i < 4; i++)
#pragma unroll
            for (int j = 0; j < 4; j++) {
                acc[i][j] = __builtin_amdgcn_mfma_f32_16x16x32_bf16(
                    af[0][i], bf[0][j], acc[i][j], 0, 0, 0);
                if constexpr (SPLIT) {
                    acc[i][j] = __builtin_amdgcn_mfma_f32_16x16x32_bf16(
                        af[0][i], bf[1][j], acc[i][j], 0, 0, 0);
                    acc[i][j] = __builtin_amdgcn_mfma_f32_16x16x32_bf16(
                        af[1][i], bf[0][j], acc[i][j], 0, 0, 0);
                }
            }
    }

    // ---- epilogue: C/D layout col=lane&15, row=(lane>>4)*4+reg ----
    float* Cg = C + (long)blockIdx.z * sC + (long)(m0 + wm) * ldc + n0 + wn;
    const int rbase = (lane >> 4) * 4;
#pragma unroll
    for (int i = 0; i < 4; i++)
#pragma unroll
        for (int r = 0; r < 4; r++) {
            float* cp = Cg + (long)(i * 16 + rbase + r) * ldc + lr;
#pragma unroll
            for (int j = 0; j < 4; j++)
                cp[j * 16] = acc[i][j][r] * scale;
        }
}

// ===========================================================================
// Phase-1 kernel: qW = (query @ W)/32, split bf16 in, hi/lo bf16 OUT.
// M=512, N=1024, K=1024. B operand = W^T planes [n][k] (pre-transposed) so
// both operands copy-stage. Tile 64x64, 4 waves (32x32 each), 128 blocks.
// ===========================================================================
__global__ __launch_bounds__(256, 2) void gemm_qw(
    const u16* __restrict__ qh, const u16* __restrict__ ql,
    const u16* __restrict__ WhT, const u16* __restrict__ WlT,
    u16* __restrict__ qWh, u16* __restrict__ qWl)
{
    __shared__ u16 As[2][64 * ASTR];
    __shared__ u16 Bs[2][64 * ASTR];

    const int tid  = threadIdx.x;
    const int lane = tid & 63;
    const int wave = tid >> 6;
    const int wm = (wave >> 1) * 32, wn = (wave & 1) * 32;
    const int lr = lane & 15, kg = (lane >> 4) * 4;
    const int m0 = blockIdx.y * 64, n0 = blockIdx.x * 64;

    const u16* Ag[2] = { qh + (long)m0 * 1024, ql + (long)m0 * 1024 };
    const u16* Bg[2] = { WhT + (long)n0 * 1024, WlT + (long)n0 * 1024 };

    f32x4 acc[2][2] = {};

    for (int k0 = 0; k0 < 1024; k0 += 32) {
        __syncthreads();
        const int row = tid >> 2, kc = (tid & 3) * 8;   // 64 rows x 32 k per plane
#pragma unroll
        for (int p = 0; p < 2; p++) {
            *(u16x8*)&As[p][row * ASTR + kc] =
                *(const u16x8*)(Ag[p] + (long)row * 1024 + k0 + kc);
            *(u16x8*)&Bs[p][row * ASTR + kc] =
                *(const u16x8*)(Bg[p] + (long)row * 1024 + k0 + kc);
        }
        __syncthreads();

        bf16x8 af[2][2], bfr[2][2];
#pragma unroll
        for (int i = 0; i < 2; i++) {
            const int r = wm + i * 16 + lr;
#pragma unroll
            for (int p = 0; p < 2; p++)
                af[p][i] = ld2(&As[p][0], r * ASTR + kg, r * ASTR + kg + 16);
        }
#pragma unroll
        for (int j = 0; j < 2; j++) {
            const int r = wn + j * 16 + lr;
#pragma unroll
            for (int p = 0; p < 2; p++)
                bfr[p][j] = ld2(&Bs[p][0], r * ASTR + kg, r * ASTR + kg + 16);
        }
#pragma unroll
        for (int i = 0; i < 2; i++)
#pragma unroll
            for (int j = 0; j < 2; j++) {
                acc[i][j] = __builtin_amdgcn_mfma_f32_16x16x32_bf16(
                    af[0][i], bfr[0][j], acc[i][j], 0, 0, 0);
                acc[i][j] = __builtin_amdgcn_mfma_f32_16x16x32_bf16(
                    af[0][i], bfr[1][j], acc[i][j], 0, 0, 0);
                acc[i][j] = __builtin_amdgcn_mfma_f32_16x16x32_bf16(
                    af[1][i], bfr[0][j], acc[i][j], 0, 0, 0);
            }
    }

    // Epilogue: scale by 1/32 and split-write hi/lo bf16 planes directly.
    const int rbase = (lane >> 4) * 4;
#pragma unroll
    for (int i = 0; i < 2; i++)
#pragma unroll
        for (int r = 0; r < 4; r++) {
            const long ro = (long)(m0 + wm + i * 16 + rbase + r) * 1024 + n0 + wn + lr;
#pragma unroll
            for (int j = 0; j < 2; j++) {
                const float v = acc[i][j][r] * (1.f / 32.f);
                const u16 h = f2bf(v);
                qWh[ro + j * 16] = h;
                qWl[ro + j * 16] = f2bf(v - bf2f(h));
            }
        }
}

// ===========================================================================
// Masked softmax over rows of 2048, in place on f32 scores; optionally also
// writes a bf16 copy (for the phase-4 A operand). One block per row.
// ===========================================================================
__global__ __launch_bounds__(256) void softmax_rows(
    float* __restrict__ att, const int* __restrict__ mask, u16* __restrict__ abf)
{
    const int  row  = blockIdx.x;                    // b*512 + k
    const int  tid  = threadIdx.x;
    const long base = (long)row * 2048 + tid * 8;

    f32x4 s0 = *(const f32x4*)(att + base);
    f32x4 s1 = *(const f32x4*)(att + base + 4);
    int4  mv0 = *(const int4*)(mask + base);
    int4  mv1 = *(const int4*)(mask + base + 4);
    const int mk[8] = {mv0.x, mv0.y, mv0.z, mv0.w, mv1.x, mv1.y, mv1.z, mv1.w};

    float x[8] = {s0[0], s0[1], s0[2], s0[3], s1[0], s1[1], s1[2], s1[3]};
#pragma unroll
    for (int j = 0; j < 8; j++) x[j] = mk[j] ? x[j] : -INFINITY;

    float mx = x[0];
#pragma unroll
    for (int j = 1; j < 8; j++) mx = fmaxf(mx, x[j]);
#pragma unroll
    for (int off = 32; off > 0; off >>= 1) mx = fmaxf(mx, __shfl_down(mx, off));

    __shared__ float red[8];
    const int wave = tid >> 6, lane = tid & 63;
    if (lane == 0) red[wave] = mx;
    __syncthreads();
    mx = fmaxf(fmaxf(red[0], red[1]), fmaxf(red[2], red[3]));

    if (mx == -INFINITY) {                           // all-masked row: zeros, not NaN
        f32x4 z = {0.f, 0.f, 0.f, 0.f};
        *(f32x4*)(att + base) = z;
        *(f32x4*)(att + base + 4) = z;
        if (abf) {
            u16x8 zb = {0, 0, 0, 0, 0, 0, 0, 0};
            *(u16x8*)(abf + base) = zb;
        }
        return;
    }

    float e[8], s = 0.f;
#pragma unroll
    for (int j = 0; j < 8; j++) { e[j] = __expf(x[j] - mx); s += e[j]; }
#pragma unroll
    for (int off = 32; off > 0; off >>= 1) s += __shfl_down(s, off);
    if (lane == 0) red[4 + wave] = s;
    __syncthreads();
    s = red[4] + red[5] + red[6] + red[7];

    const float inv = 1.f / s;
    float o[8];
#pragma unroll
    for (int j = 0; j < 8; j++) o[j] = e[j] * inv;
    f32x4 o0 = {o[0], o[1], o[2], o[3]}, o1 = {o[4], o[5], o[6], o[7]};
    *(f32x4*)(att + base) = o0;
    *(f32x4*)(att + base + 4) = o1;
    if (abf) {
        u16x8 pb;
#pragma unroll
        for (int j = 0; j < 8; j++) pb[j] = f2bf(o[j]);
        *(u16x8*)(abf + base) = pb;
    }
}

// ===========================================================================
extern "C" void kernel_launch(void* const* d_in, const int* in_sizes, int n_in,
                              void* d_out, int out_size, void* d_ws, size_t ws_size,
                              hipStream_t stream)
{
    const float* query = nullptr;   // 512*1024      = 524288
    const float* key   = nullptr;   // 16*2048*1024  = 33554432
    const float* W     = nullptr;   // 1024*1024     = 1048576
    const int*   mask  = nullptr;   // 16*512*2048   = 16777216
    for (int i = 0; i < n_in; i++) {
        switch (in_sizes[i]) {
            case 524288:   query = (const float*)d_in[i]; break;
            case 33554432: key   = (const float*)d_in[i]; break;
            case 1048576:  W     = (const float*)d_in[i]; break;
            case 16777216: mask  = (const int*)d_in[i];   break;
        }
    }

    float* out = (float*)d_out;                     // [16,512,1024] f32
    float* att = out + (long)16 * 512 * 1024;       // [16,512,2048] f32

    const long KEY_E = 16L * 2048 * 1024;           // 33,554,432
    const long ATT_E = 16L * 512 * 2048;            // 16,777,216
    const long QW_E  = 512L * 1024;                 //    524,288
    const long W_E   = 1024L * 1024;                //  1,048,576
    // ws layout: key_hi | key_lo(-> key_hT after phase 2) | att_b | qW_hi | qW_lo
    // Phase-1 scratch (q_hi,q_lo,W_hi,W_lo,W_hiT,W_loT = 5.25M u16) aliases into
    // att_b (16.8M u16, dead until softmax). WS_NEED identical to round 4.
    const size_t WS_NEED = (size_t)(2 * KEY_E + ATT_E + 2 * QW_E) * 2;

    if (ws_size >= WS_NEED && d_ws != nullptr) {
        u16* key_hi = (u16*)d_ws;
        u16* key_lo = key_hi + KEY_E;   // becomes key_hT after phase 2
        u16* att_b  = key_lo + KEY_E;
        u16* qW_hi  = att_b + ATT_E;
        u16* qW_lo  = qW_hi + QW_E;
        // phase-1 scratch aliased into att_b (all dead by softmax time):
        u16* q_hi   = att_b;
        u16* q_lo   = q_hi + QW_E;
        u16* W_hi   = q_lo + QW_E;
        u16* W_lo   = W_hi + W_E;
        u16* W_hiT  = W_lo + W_E;
        u16* W_loT  = W_hiT + W_E;

        // 0) split key / query / W into hi+lo bf16 planes (memory-bound)
        split_f32<<<dim3(4096), 256, 0, stream>>>(key, key_hi, key_lo, KEY_E / 4);
        split_f32<<<dim3(512),  256, 0, stream>>>(query, q_hi, q_lo, QW_E / 4);
        split_f32<<<dim3(1024), 256, 0, stream>>>(W, W_hi, W_lo, W_E / 4);

        // 0b) transpose W planes: [1024 k][1024 n] -> [1024 n][1024 k]
        transpose_bf16<<<dim3(16, 16, 1), 256, 0, stream>>>(W_hi, W_hiT, 1024, 1024);
        transpose_bf16<<<dim3(16, 16, 1), 256, 0, stream>>>(W_lo, W_loT, 1024, 1024);

        // 1) qW hi/lo = (query @ W) / 32   [512 x 1024], 128 blocks, copy-staged
        gemm_qw<<<dim3(16, 8, 1), 256, 0, stream>>>(
            q_hi, q_lo, W_hiT, W_loT, qW_hi, qW_lo);

        // 2) S[b] = qW @ key[b]^T    [512 x 2048], K=1024, split bf16 GEMM
        gemm_bf16<true><<<dim3(16, 4, 16), 256, 0, stream>>>(
            qW_hi, qW_lo, key_hi, key_lo, att,
            1024, 1024, 1024, 2048,
            0L, (long)2048 * 1024, (long)512 * 2048, 1.f);

        // 2b) transpose key_hi [b][2048 n][1024 d] -> key_hT [b][1024 d][2048 n]
        //     into the key_lo slot (key_lo dead after phase 2).
        u16* key_hT = key_lo;
        transpose_bf16<<<dim3(16, 32, 16), 256, 0, stream>>>(
            key_hi, key_hT, 2048, 1024);

        // 3) masked softmax, dual-write f32 + bf16 (overwrites q/W scratch)
        softmax_rows<<<dim3(16 * 512), 256, 0, stream>>>(att, mask, att_b);

        // 4) out[b] = att[b] @ key[b]  [512 x 1024], K=2048, copy-staged GEMM
        gemm_bf16<false><<<dim3(8, 4, 16), 256, 0, stream>>>(
            att_b, nullptr, key_hT, nullptr, out,
            2048, 2048, 2048, 1024,
            (long)512 * 2048, (long)1024 * 2048, (long)512 * 1024, 1.f);
    } else {
        // -------- fallback: round-1 path, no workspace --------
        float* qW = out;    // f32 scratch in out region (dead before phase 4)
        gemm_f32conv<false, true><<<dim3(8, 4, 1), 256, 0, stream>>>(
            query, W, qW, 1024, 1024, 1024, 1024, 0L, 0L, 0L, 1.f / 32.f);
        gemm_f32conv<true, true><<<dim3(16, 4, 16), 256, 0, stream>>>(
            qW, key, att, 1024, 1024, 1024, 2048,
            0L, (long)2048 * 1024, (long)512 * 2048, 1.f);
        softmax_rows<<<dim3(16 * 512), 256, 0, stream>>>(att, mask, nullptr);
        gemm_f32conv<false, false><<<dim3(8, 4, 16), 256, 0, stream>>>(
            att, key, out, 2048, 2048, 1024, 1024,
            (long)512 * 2048, (long)2048 * 1024, (long)512 * 1024, 1.f);
    }
}